// Round 4
// baseline (115.333 us; speedup 1.0000x reference)
//
#include <hip/hip_runtime.h>
#include <cstdint>
#include <cstddef>

// Problem constants (match reference file)
#define BB 4
#define MM 8192
#define NN 6890
#define NSEG 64
#define SEGN 108          // ceil(6890/64); last segment has 86
#define SEGP 112          // SEGN padded to multiple of G
#define G 16              // tournament group size
#define CHUNKS 2          // MM / MQ
#define MQ 4096           // queries per nn block (TPB * QT)
#define QT 8              // queries per thread (8 independent scalar chains)
#define TPB 512
#define NQ (BB * MM)      // 32768 queries

static constexpr float MIN_T2 = 0.005f * 0.005f;   // MIN_DIST_THRESH^2

// ws layout (bytes):
//   [0, 16777216)            u64 partials[NSEG][NQ]  (d2_bits<<32 | idx)
//   [16777216, +1024)        float bsum[256]
//   [16778240, +1024)        int   bmatch[256]
#define OFF_BSUM   16777216
#define OFF_BMATCH (16777216 + 1024)

static __device__ __forceinline__ unsigned long long u64min(
    unsigned long long a, unsigned long long b) { return a < b ? a : b; }

// Kernel 1: per-(batch, m-chunk, n-segment) NN.
// R3 post-mortem: packed tournament = 8 cy per query-cand; R4 cuts to 7 cy
// via SCALAR chains + candidate pairs: fminf(fminf(e0,e1),gm) folds to one
// v_min3_f32 (3 fma + 0.5 min3 per query-cand, -12.5% issue). Scan and
// recovery now use the IDENTICAL scalar fmaf chain, so the equality rescan
// is exact by construction. TPB=512/CHUNKS=2 halves block count (512 blocks
// = 2/CU x 8 waves = 4 waves/SIMD, same occupancy) halving prologue work.
// Tiebreaks preserved: strict < across groups -> earliest group; downward
// equality scan -> lowest in-group index; u64 key low-bits -> lowest global
// index across segments (all-inf row degenerates to idx 0 like reference).
__global__ __launch_bounds__(TPB) void nn_kernel(
    const float* __restrict__ cloth, const float* __restrict__ vt,
    const int* __restrict__ valid, unsigned long long* __restrict__ partials)
{
    __shared__ float4 lds[SEGP];
    int bid   = blockIdx.x;            // 512 blocks = 2/CU
    int seg   = bid & (NSEG - 1);
    int chunk = (bid >> 6) & (CHUNKS - 1);
    int b     = bid >> 7;
    int n0    = seg * SEGN;
    int segn  = (NN - n0 < SEGN) ? (NN - n0) : SEGN;
    int ngroups = (segn + G - 1) / G;
    int npad    = ngroups * G;

    // fused candidate prep: (-2x,-2y,-2z, s2 or +inf if invalid); pads inert
    if (threadIdx.x < npad) {
        float4 v = make_float4(0.0f, 0.0f, 0.0f, __builtin_inff());
        if (threadIdx.x < segn) {
            int n = n0 + threadIdx.x;
            const float* p = vt + ((size_t)b * NN + n) * 3;
            float x = p[0], y = p[1], z = p[2];
            float s2 = x * x + y * y + z * z;
            if (valid[b * NN + n] <= 0) s2 = __builtin_inff();
            v = make_float4(-2.0f * x, -2.0f * y, -2.0f * z, s2);
        }
        lds[threadIdx.x] = v;
    }

    float qx[QT], qy[QT], qz[QT], qc2[QT], bd[QT];
    int gb[QT];
    int m0 = chunk * MQ + threadIdx.x;
#pragma unroll
    for (int j = 0; j < QT; j++) {
        int m = m0 + j * TPB;
        const float* p = cloth + ((size_t)b * MM + m) * 3;
        float x = p[0], y = p[1], z = p[2];
        qx[j] = x; qy[j] = y; qz[j] = z;
        qc2[j] = x * x + y * y + z * z;
        bd[j] = __builtin_inff();
        gb[j] = 0;
    }
    __syncthreads();

    // Hot loop: UNFILTERED value-min in shifted space e = s2 - 2 c.s,
    // group tournament, candidates in pairs -> v_min3_f32 per pair.
    for (int g = 0; g < ngroups; g++) {
        int base = g << 4;
        float gm[QT];
#pragma unroll
        for (int j = 0; j < QT; j++) gm[j] = __builtin_inff();
#pragma unroll
        for (int t = 0; t < G; t += 2) {
            float4 c0 = lds[base + t];
            float4 c1 = lds[base + t + 1];
#pragma unroll
            for (int j = 0; j < QT; j++) {
                float e0 = fmaf(c0.x, qx[j],
                           fmaf(c0.y, qy[j], fmaf(c0.z, qz[j], c0.w)));
                float e1 = fmaf(c1.x, qx[j],
                           fmaf(c1.y, qy[j], fmaf(c1.z, qz[j], c1.w)));
                gm[j] = fminf(fminf(e0, e1), gm[j]);   // -> v_min3_f32
            }
        }
#pragma unroll
        for (int j = 0; j < QT; j++) {
            bool ok = gm[j] < bd[j];
            bd[j] = ok ? gm[j] : bd[j];
            gb[j] = ok ? g : gb[j];
        }
    }

    // index recovery: equality rescan of the winning group (16 steps,
    // downward -> lowest index). Same scalar fmaf chain as the scan, and
    // min3 is an exact min -> e == tgt always found.
    int bi[QT];
#pragma unroll
    for (int j = 0; j < QT; j++) {
        int base = gb[j] << 4;
        float tgt = bd[j];
        int mloc = G;                    // G = not found (unreachable)
#pragma unroll
        for (int t = G - 1; t >= 0; t--) {
            float4 c = lds[base + t];
            float e = fmaf(c.x, qx[j], fmaf(c.y, qy[j], fmaf(c.z, qz[j], c.w)));
            mloc = (e == tgt) ? t : mloc;
        }
        int gi = n0 + base + ((mloc < G) ? mloc : 0);
        bi[j] = (gi > NN - 1) ? (NN - 1) : gi;   // pad corner clamp
    }

    // rare fallback: unfiltered min is a too-close candidate -> rescan this
    // segment with the full filter (if the min passes, all candidates do).
#pragma unroll
    for (int j = 0; j < QT; j++) {
        float tmin = MIN_T2 - qc2[j];
        if (bd[j] < tmin) {
            float fb = __builtin_inff(); int fi = 0;
            for (int i = 0; i < segn; i++) {
                float4 c = lds[i];
                float e = fmaf(c.x, qx[j], fmaf(c.y, qy[j], fmaf(c.z, qz[j], c.w)));
                bool ok = (e >= tmin) && (e < fb);
                fb = ok ? e : fb;
                fi = ok ? (n0 + i) : fi;
            }
            bd[j] = fb; bi[j] = fi;
        }
    }

    // coalesced partial store: d2 = e + qc2 >= MIN_T2 > 0 (or +inf), so
    // float bits order correctly as unsigned; low 32 bits = idx tiebreak.
#pragma unroll
    for (int j = 0; j < QT; j++) {
        int q = b * MM + m0 + j * TPB;
        float d2 = bd[j] + qc2[j];
        unsigned long long key =
            ((unsigned long long)__float_as_uint(d2) << 32) | (unsigned)bi[j];
        partials[(size_t)seg * NQ + q] = key;
    }
}

// Kernel 2: per-query u64-min over NSEG=64 segment partials, fully unrolled
// with 8 independent accumulators so all loads are in flight. Then gather
// target, contribution, block-reduce.
__global__ __launch_bounds__(128) void finalize_kernel(
    const unsigned long long* __restrict__ partials,
    const int* __restrict__ smpl_idx, const float* __restrict__ sdf,
    const int* __restrict__ cloth_idx, const float* __restrict__ sdf_thresh,
    const float* __restrict__ dist_thresh,
    float* __restrict__ bsum, int* __restrict__ bmatch)
{
    int q = blockIdx.x * 128 + threadIdx.x;   // 256 blocks x 128 = NQ
    int b = q >> 13;
    unsigned long long mm[8];
#pragma unroll
    for (int k = 0; k < 8; k++) mm[k] = ~0ULL;
#pragma unroll
    for (int s = 0; s < NSEG; s += 8) {
#pragma unroll
        for (int k = 0; k < 8; k++)
            mm[k] = u64min(mm[k], partials[(size_t)(s + k) * NQ + q]);
    }
    unsigned long long key =
        u64min(u64min(u64min(mm[0], mm[1]), u64min(mm[2], mm[3])),
               u64min(u64min(mm[4], mm[5]), u64min(mm[6], mm[7])));

    float d2  = __uint_as_float((unsigned)(key >> 32));
    int   idx = (int)(unsigned)(key & 0xFFFFFFFFu);
    int target = smpl_idx[b * NN + idx];
    int ci0 = cloth_idx[0], ci1 = cloth_idx[1];
    bool match = (target == ci0) || (target == ci1);
    bool near_ = sqrtf(d2) < dist_thresh[0];     // inf -> false
    float s = sdf[q];
    float contrib = near_ ? (match ? fabsf(s) : fabsf(s - sdf_thresh[0])) : 0.0f;
    int mt = match ? 1 : 0;

    for (int off = 32; off > 0; off >>= 1) {
        contrib += __shfl_down(contrib, off, 64);
        mt      |= __shfl_down(mt, off, 64);
    }
    __shared__ float wsum[2];
    __shared__ int   wmat[2];
    int wave = threadIdx.x >> 6;
    if ((threadIdx.x & 63) == 0) { wsum[wave] = contrib; wmat[wave] = mt; }
    __syncthreads();
    if (threadIdx.x == 0) {
        bsum[blockIdx.x]   = wsum[0] + wsum[1];
        bmatch[blockIdx.x] = wmat[0] | wmat[1];
    }
}

// Kernel 3: 256 block-partials -> 4 batch losses (64 partials per batch,
// one wave per batch).
__global__ __launch_bounds__(256) void reduce_kernel(
    const float* __restrict__ bs, const int* __restrict__ bm,
    float* __restrict__ out)
{
    int t = threadIdx.x;          // batch = t>>6
    float s = bs[t];
    int   m = bm[t];
    for (int off = 32; off > 0; off >>= 1) {
        s += __shfl_down(s, off, 64);
        m |= __shfl_down(m, off, 64);
    }
    if ((t & 63) == 0)
        out[t >> 6] = s * (1.0f / (float)MM) * (m ? 1.0f : 0.0f);
}

extern "C" void kernel_launch(void* const* d_in, const int* in_sizes, int n_in,
                              void* d_out, int out_size, void* d_ws, size_t ws_size,
                              hipStream_t stream)
{
    const float* sdf         = (const float*)d_in[0];
    const float* cloth       = (const float*)d_in[1];
    const int*   smpl_idx    = (const int*)d_in[2];
    const int*   valid       = (const int*)d_in[3];
    const int*   cloth_idx   = (const int*)d_in[4];
    const float* sdf_thresh  = (const float*)d_in[5];
    const float* dist_thresh = (const float*)d_in[6];
    const float* vt          = (const float*)d_in[7];

    char* ws = (char*)d_ws;
    unsigned long long* partials = (unsigned long long*)ws;
    float* bsum   = (float*)(ws + OFF_BSUM);
    int*   bmatch = (int*)(ws + OFF_BMATCH);

    nn_kernel<<<BB * CHUNKS * NSEG, TPB, 0, stream>>>(cloth, vt, valid, partials);
    finalize_kernel<<<NQ / 128, 128, 0, stream>>>(
        partials, smpl_idx, sdf, cloth_idx, sdf_thresh, dist_thresh,
        bsum, bmatch);
    reduce_kernel<<<1, 256, 0, stream>>>(bsum, bmatch, (float*)d_out);
}

// Round 5
// 108.376 us; speedup vs baseline: 1.0642x; 1.0642x over previous
//
#include <hip/hip_runtime.h>
#include <cstdint>
#include <cstddef>

// Problem constants (match reference file)
#define BB 4
#define MM 8192
#define NN 6890
#define NSEG 64
#define SEGN 108          // ceil(6890/64); last segment has 86
#define G 16              // tournament group size
#define GMAX 7            // max groups per segment (108/16 -> 7)
#define GSTRIDE 17        // group stride in float4 slots (bank-spread pad)
#define CHUNKS 2          // MM / MQ
#define MQ 4096           // queries per nn block (TPB * QT)
#define QT 8              // queries per thread (8 independent scalar chains)
#define TPB 512
#define NQ (BB * MM)      // 32768 queries

static constexpr float MIN_T2 = 0.005f * 0.005f;   // MIN_DIST_THRESH^2

// ws layout (bytes):
//   [0, 16777216)            u64 partials[NSEG][NQ]  (d2_bits<<32 | idx)
//   [16777216, +1024)        float bsum[256]
//   [16778240, +1024)        int   bmatch[256]
#define OFF_BSUM   16777216
#define OFF_BMATCH (16777216 + 1024)

static __device__ __forceinline__ unsigned long long u64min(
    unsigned long long a, unsigned long long b) { return a < b ? a : b; }

// Kernel 1: per-(batch, m-chunk, n-segment) NN, group tournament.
// R4 post-mortem: SQ_LDS_BANK_CONFLICT = 1.09e7 (was 0 in R1). Cause: the
// index-recovery rescan reads lds[16*gb[j] + t] with gb varying PER LANE;
// float4 index k -> dword bank (4k+w)%32, and k=16g+t gives (16t+w)%32 --
// independent of g, so all 7 groups' slots for a given (t,w) share ONE bank
// -> 7-way conflict on every dword of 128 divergent b128 reads/thread.
// R5 fix: group stride 17 float4s. k=17g+t -> bank (4g+4t+w)%32; the 7
// groups' b128 windows {4g+4t..+3} are pairwise-disjoint bank sets ->
// divergent recovery reads are conflict-free by construction. Hot-loop
// reads remain wave-uniform broadcasts. Arithmetic (scan, recovery chain,
// tiebreaks, u64 key) bit-identical to the passing R4 kernel.
__global__ __launch_bounds__(TPB) void nn_kernel(
    const float* __restrict__ cloth, const float* __restrict__ vt,
    const int* __restrict__ valid, unsigned long long* __restrict__ partials)
{
    __shared__ float4 lds[GMAX * GSTRIDE];   // 119 float4 = 1904 B
    int bid   = blockIdx.x;            // 512 blocks = 2/CU
    int seg   = bid & (NSEG - 1);
    int chunk = (bid >> 6) & (CHUNKS - 1);
    int b     = bid >> 7;
    int n0    = seg * SEGN;
    int segn  = (NN - n0 < SEGN) ? (NN - n0) : SEGN;
    int ngroups = (segn + G - 1) / G;
    int npad    = ngroups * G;

    // fused candidate prep: (-2x,-2y,-2z, s2 or +inf if invalid); pads inert
    if (threadIdx.x < npad) {
        float4 v = make_float4(0.0f, 0.0f, 0.0f, __builtin_inff());
        if (threadIdx.x < segn) {
            int n = n0 + threadIdx.x;
            const float* p = vt + ((size_t)b * NN + n) * 3;
            float x = p[0], y = p[1], z = p[2];
            float s2 = x * x + y * y + z * z;
            if (valid[b * NN + n] <= 0) s2 = __builtin_inff();
            v = make_float4(-2.0f * x, -2.0f * y, -2.0f * z, s2);
        }
        int slot = (threadIdx.x >> 4) * GSTRIDE + (threadIdx.x & (G - 1));
        lds[slot] = v;
    }

    float qx[QT], qy[QT], qz[QT], qc2[QT], bd[QT];
    int gb[QT];
    int m0 = chunk * MQ + threadIdx.x;
#pragma unroll
    for (int j = 0; j < QT; j++) {
        int m = m0 + j * TPB;
        const float* p = cloth + ((size_t)b * MM + m) * 3;
        float x = p[0], y = p[1], z = p[2];
        qx[j] = x; qy[j] = y; qz[j] = z;
        qc2[j] = x * x + y * y + z * z;
        bd[j] = __builtin_inff();
        gb[j] = 0;
    }
    __syncthreads();

    // Hot loop: UNFILTERED value-min in shifted space e = s2 - 2 c.s,
    // group tournament, candidates in pairs -> fminf fold.
    for (int g = 0; g < ngroups; g++) {
        int base = g * GSTRIDE;
        float gm[QT];
#pragma unroll
        for (int j = 0; j < QT; j++) gm[j] = __builtin_inff();
#pragma unroll
        for (int t = 0; t < G; t += 2) {
            float4 c0 = lds[base + t];
            float4 c1 = lds[base + t + 1];
#pragma unroll
            for (int j = 0; j < QT; j++) {
                float e0 = fmaf(c0.x, qx[j],
                           fmaf(c0.y, qy[j], fmaf(c0.z, qz[j], c0.w)));
                float e1 = fmaf(c1.x, qx[j],
                           fmaf(c1.y, qy[j], fmaf(c1.z, qz[j], c1.w)));
                gm[j] = fminf(fminf(e0, e1), gm[j]);
            }
        }
#pragma unroll
        for (int j = 0; j < QT; j++) {
            bool ok = gm[j] < bd[j];
            bd[j] = ok ? gm[j] : bd[j];
            gb[j] = ok ? g : gb[j];
        }
    }

    // index recovery: equality rescan of the winning group (16 steps,
    // downward -> lowest index). Same scalar fmaf chain as the scan; min is
    // exact -> e == tgt always found. Reads are divergent across lanes but
    // conflict-free under GSTRIDE=17 (disjoint bank windows per group).
    int bi[QT];
#pragma unroll
    for (int j = 0; j < QT; j++) {
        int base = gb[j] * GSTRIDE;
        float tgt = bd[j];
        int mloc = G;                    // G = not found (unreachable)
#pragma unroll
        for (int t = G - 1; t >= 0; t--) {
            float4 c = lds[base + t];
            float e = fmaf(c.x, qx[j], fmaf(c.y, qy[j], fmaf(c.z, qz[j], c.w)));
            mloc = (e == tgt) ? t : mloc;
        }
        int gi = n0 + (gb[j] << 4) + ((mloc < G) ? mloc : 0);
        bi[j] = (gi > NN - 1) ? (NN - 1) : gi;   // pad corner clamp
    }

    // rare fallback: unfiltered min is a too-close candidate -> rescan this
    // segment with the full filter (if the min passes, all candidates do).
#pragma unroll
    for (int j = 0; j < QT; j++) {
        float tmin = MIN_T2 - qc2[j];
        if (bd[j] < tmin) {
            float fb = __builtin_inff(); int fi = 0;
            for (int i = 0; i < segn; i++) {
                float4 c = lds[(i >> 4) * GSTRIDE + (i & (G - 1))];
                float e = fmaf(c.x, qx[j], fmaf(c.y, qy[j], fmaf(c.z, qz[j], c.w)));
                bool ok = (e >= tmin) && (e < fb);
                fb = ok ? e : fb;
                fi = ok ? (n0 + i) : fi;
            }
            bd[j] = fb; bi[j] = fi;
        }
    }

    // coalesced partial store: d2 = e + qc2 >= MIN_T2 > 0 (or +inf), so
    // float bits order correctly as unsigned; low 32 bits = idx tiebreak.
#pragma unroll
    for (int j = 0; j < QT; j++) {
        int q = b * MM + m0 + j * TPB;
        float d2 = bd[j] + qc2[j];
        unsigned long long key =
            ((unsigned long long)__float_as_uint(d2) << 32) | (unsigned)bi[j];
        partials[(size_t)seg * NQ + q] = key;
    }
}

// Kernel 2: per-query u64-min over NSEG=64 segment partials, fully unrolled
// with 8 independent accumulators so all loads are in flight. Then gather
// target, contribution, block-reduce.
__global__ __launch_bounds__(128) void finalize_kernel(
    const unsigned long long* __restrict__ partials,
    const int* __restrict__ smpl_idx, const float* __restrict__ sdf,
    const int* __restrict__ cloth_idx, const float* __restrict__ sdf_thresh,
    const float* __restrict__ dist_thresh,
    float* __restrict__ bsum, int* __restrict__ bmatch)
{
    int q = blockIdx.x * 128 + threadIdx.x;   // 256 blocks x 128 = NQ
    int b = q >> 13;
    unsigned long long mm[8];
#pragma unroll
    for (int k = 0; k < 8; k++) mm[k] = ~0ULL;
#pragma unroll
    for (int s = 0; s < NSEG; s += 8) {
#pragma unroll
        for (int k = 0; k < 8; k++)
            mm[k] = u64min(mm[k], partials[(size_t)(s + k) * NQ + q]);
    }
    unsigned long long key =
        u64min(u64min(u64min(mm[0], mm[1]), u64min(mm[2], mm[3])),
               u64min(u64min(mm[4], mm[5]), u64min(mm[6], mm[7])));

    float d2  = __uint_as_float((unsigned)(key >> 32));
    int   idx = (int)(unsigned)(key & 0xFFFFFFFFu);
    int target = smpl_idx[b * NN + idx];
    int ci0 = cloth_idx[0], ci1 = cloth_idx[1];
    bool match = (target == ci0) || (target == ci1);
    bool near_ = sqrtf(d2) < dist_thresh[0];     // inf -> false
    float s = sdf[q];
    float contrib = near_ ? (match ? fabsf(s) : fabsf(s - sdf_thresh[0])) : 0.0f;
    int mt = match ? 1 : 0;

    for (int off = 32; off > 0; off >>= 1) {
        contrib += __shfl_down(contrib, off, 64);
        mt      |= __shfl_down(mt, off, 64);
    }
    __shared__ float wsum[2];
    __shared__ int   wmat[2];
    int wave = threadIdx.x >> 6;
    if ((threadIdx.x & 63) == 0) { wsum[wave] = contrib; wmat[wave] = mt; }
    __syncthreads();
    if (threadIdx.x == 0) {
        bsum[blockIdx.x]   = wsum[0] + wsum[1];
        bmatch[blockIdx.x] = wmat[0] | wmat[1];
    }
}

// Kernel 3: 256 block-partials -> 4 batch losses (64 partials per batch,
// one wave per batch).
__global__ __launch_bounds__(256) void reduce_kernel(
    const float* __restrict__ bs, const int* __restrict__ bm,
    float* __restrict__ out)
{
    int t = threadIdx.x;          // batch = t>>6
    float s = bs[t];
    int   m = bm[t];
    for (int off = 32; off > 0; off >>= 1) {
        s += __shfl_down(s, off, 64);
        m |= __shfl_down(m, off, 64);
    }
    if ((t & 63) == 0)
        out[t >> 6] = s * (1.0f / (float)MM) * (m ? 1.0f : 0.0f);
}

extern "C" void kernel_launch(void* const* d_in, const int* in_sizes, int n_in,
                              void* d_out, int out_size, void* d_ws, size_t ws_size,
                              hipStream_t stream)
{
    const float* sdf         = (const float*)d_in[0];
    const float* cloth       = (const float*)d_in[1];
    const int*   smpl_idx    = (const int*)d_in[2];
    const int*   valid       = (const int*)d_in[3];
    const int*   cloth_idx   = (const int*)d_in[4];
    const float* sdf_thresh  = (const float*)d_in[5];
    const float* dist_thresh = (const float*)d_in[6];
    const float* vt          = (const float*)d_in[7];

    char* ws = (char*)d_ws;
    unsigned long long* partials = (unsigned long long*)ws;
    float* bsum   = (float*)(ws + OFF_BSUM);
    int*   bmatch = (int*)(ws + OFF_BMATCH);

    nn_kernel<<<BB * CHUNKS * NSEG, TPB, 0, stream>>>(cloth, vt, valid, partials);
    finalize_kernel<<<NQ / 128, 128, 0, stream>>>(
        partials, smpl_idx, sdf, cloth_idx, sdf_thresh, dist_thresh,
        bsum, bmatch);
    reduce_kernel<<<1, 256, 0, stream>>>(bsum, bmatch, (float*)d_out);
}